// Round 4
// baseline (817.641 us; speedup 1.0000x reference)
//
#include <hip/hip_runtime.h>
#include <cstdint>
#include <cstddef>

// ---------------------------------------------------------------------------
// LlamaAttention prefill, MI355X/gfx950.
// Round 7: fine-grained granules + in-register fused RoPE.
//  R6 post-mortem: per-CU per-K-tile MFMA ~=1080 cyc, LDS-read ~=860-1540,
//  observed 2194 ~= serial sum -> pipes still ping-pong (granule too coarse).
//  Changes (sync structure -- ring-4 buffers, one vmcnt(4)+barrier per tile,
//  3-ahead staging -- IDENTICAL to round 6; only instruction grouping):
//   - 4 granules of 8 MFMA per K-tile; each granule = {4 ds_reads or 2 DMA;
//     sched_barrier; setprio1; 8 MFMA; setprio0}. Operands of every burst
//     were issued >=2 granules earlier -> counted-small lgkm waits, LDS
//     runs under the MFMA pipe.
//   - Wave shape 4M x 2N (wave tile 64x128): same traffic/MFMA count, but a
//     wave owns whole heads -> RoPE pairs (d,d+64) are in-lane (ni, ni+4).
//   - RoPE fused into GEMM1 epilogue (register rotate, __sincosf, reads
//     pos[]/inv_freq[]); rope_kernel deleted.
// Workspace layout (bytes): total 176,160,768 (168 MiB)
//   [0,32M)      Xbf  (4096x4096 bf16)  -- reused as AO after GEMM1
//   [32M,80M)    Wqkvt (6144x4096 bf16, B^T)
//   [80M,112M)   Wot   (4096x4096 bf16, B^T)
//   [112M,160M)  QKV   (4096x6144 bf16, Q/K pre-roped; V section poisoned)
//   [160M,168M)  Vt    (32 bh x 128 d x 1024 p bf16)
// ---------------------------------------------------------------------------

typedef unsigned short u16;
typedef __bf16 bf16x8 __attribute__((ext_vector_type(8)));
typedef float  f32x4  __attribute__((ext_vector_type(4)));

#define SEQ 1024
#define QKV_COLS 6144
#define NHEAD 32
#define NKVH 8
#define HDIM 128

__device__ __forceinline__ u16 f2bf(float f) {
  union { float f; uint32_t u; } v; v.f = f;
  return (u16)((v.u + 0x7fffu + ((v.u >> 16) & 1u)) >> 16);  // RNE
}
__device__ __forceinline__ float bf2f(u16 x) {
  union { uint32_t u; float f; } v; v.u = ((uint32_t)x) << 16;
  return v.f;
}

// async global->LDS DMA, 16B per lane. LDS dest: wave-uniform base + lane*16.
typedef __attribute__((address_space(1))) const uint32_t g_u32;
typedef __attribute__((address_space(3))) uint32_t l_u32;
__device__ __forceinline__ void async_copy16(const u16* g, u16* lds_base) {
  __builtin_amdgcn_global_load_lds((g_u32*)g, (l_u32*)lds_base, 16, 0, 0);
}

// ---------------- fp32 -> bf16 flat cast (X) ----------------
__global__ void cast_f32_bf16(const float* __restrict__ in, u16* __restrict__ out, int n) {
  int i = (blockIdx.x * 256 + threadIdx.x) * 4;
  if (i >= n) return;
  float4 v = *(const float4*)&in[i];
  uint2 pk;
  pk.x = (uint32_t)f2bf(v.x) | ((uint32_t)f2bf(v.y) << 16);
  pk.y = (uint32_t)f2bf(v.z) | ((uint32_t)f2bf(v.w) << 16);
  *(uint2*)&out[i] = pk;
}

// ---------------- transpose fp32 [R][C] -> bf16 [C][R] ----------------
__global__ void transpose_f32_bf16(const float* __restrict__ in, u16* __restrict__ out,
                                   int R, int C) {
  __shared__ float tile[32][33];
  int c0 = blockIdx.x * 32, r0 = blockIdx.y * 32;
  int tx = threadIdx.x, ty = threadIdx.y;
  tile[ty][tx] = in[(size_t)(r0 + ty) * C + c0 + tx];
  __syncthreads();
  out[(size_t)(c0 + ty) * R + r0 + tx] = f2bf(tile[tx][ty]);
}

// ---------------- bf16 GEMM: C[M][N] = A[M][K] * Bt[N][K]^T ----------------
// 256x256 tile, 8 waves (4Mx2N), wave tile 64x128 (4x8 frags of 16x16x32).
// BK=32. 4 LDS buffers; staging 3 tiles ahead; boundary = vmcnt(4)+s_barrier
// (publishes tile t+2; t+1 was published at the previous boundary, so
// next-tile register prefetch during tile t is legal).
// Per tile, 4 granules of 8 MFMA with distributed reads:
//  G1: read bh[0..3] (B cols 64-127, buf t)      ; MFMA acc[0..1][0..3]
//  G2: read a2[0..3] (all A rows, buf t+1)       ; MFMA acc[2..3][0..3]
//  G3: read b2[0..3] (B cols 0-63, buf t+1); DMA A(t+3); MFMA acc[0..1][4..7]
//  G4: DMA B(t+3)                                ; MFMA acc[2..3][4..7]
//  boundary: vmcnt(4) (t+3 stays in flight) + s_barrier; a<=a2, b<=b2.
// Frag-read swizzle: LDS chunk slot j of row r holds global chunk
// j ^ (r&3) ^ ((r>>2)&3); row bases are multiples of 16 so the read offset
// depends only on the lane: sl = (qd ^ (l15&3) ^ (l15>>2))*8.
// MODE 0: V col-tiles (>=5120) -> Vt[bh][d][p]; Q/K tiles get RoPE applied
//         in-register (pairs (ni,ni+4) = cols d,d+64 of the wave's head).
// MODE 1: f32 C.
template <int MODE>
__global__ __launch_bounds__(512, 2) void gemm_bt(const u16* __restrict__ A,
                                                  const u16* __restrict__ Bt,
                                                  void* __restrict__ Cv,
                                                  u16* __restrict__ Vt,
                                                  const float* __restrict__ invf,
                                                  const int* __restrict__ pos,
                                                  int M, int N, int K, int ldc,
                                                  int nbx) {
  __shared__ __align__(16) u16 smem[4][2][256 * 32];   // [buf][A|B], 128 KiB

  const int tid = threadIdx.x;
  const int lane = tid & 63, wave = tid >> 6;
  const int l15 = lane & 15, qd = lane >> 4;
  const int wm = wave & 3, wn = wave >> 2;             // 4M x 2N

  // XCD-aware bijective block swizzle (nwg % 8 == 0 for our shapes)
  const int nwg = gridDim.x;
  const int bid = (int)blockIdx.x;
  const int swz = (bid & 7) * (nwg >> 3) + (bid >> 3);
  const int bx = swz % nbx, by = swz / nbx;
  const int row0 = by * 256, col0 = bx * 256;

  const int sl = (qd ^ (l15 & 3) ^ (l15 >> 2)) * 8;   // swizzled frag chunk

  // staging: per-thread pre-swizzled global source offset + wave LDS base
  int soff[2], cb[2];
#pragma unroll
  for (int call = 0; call < 2; ++call) {
    const int c = call * 512 + tid;              // linear LDS 16B-chunk index
    const int r = c >> 2, j = c & 3;             // row, chunk slot
    const int src = j ^ (r & 3) ^ ((r >> 2) & 3);
    soff[call] = r * K + src * 8;
    cb[call] = (call * 512 + wave * 64) * 8;     // wave-uniform dest (u16 idx)
  }

  const u16* Ab = A + (size_t)row0 * K;
  const u16* Bb = Bt + (size_t)col0 * K;
  const int NT = K >> 5;                         // K-tiles (K=4096 -> 128)

  f32x4 acc[4][8] = {};

  // -------- prologue: stage tiles 0..2 (12 loads), publish 0 and 1 --------
#pragma unroll
  for (int tt = 0; tt < 3; ++tt) {
#pragma unroll
    for (int call = 0; call < 2; ++call)
      async_copy16(&Ab[tt * 32 + soff[call]], &smem[tt][0][cb[call]]);
#pragma unroll
    for (int call = 0; call < 2; ++call)
      async_copy16(&Bb[tt * 32 + soff[call]], &smem[tt][1][cb[call]]);
  }
  asm volatile("s_waitcnt vmcnt(4)" ::: "memory");   // tiles 0,1 landed
  __builtin_amdgcn_s_barrier();
  asm volatile("" ::: "memory");

  // register prefetch: tile-0 A (all 4 frags) + B cols 0-63
  bf16x8 a[4], b[4];
#pragma unroll
  for (int i = 0; i < 4; ++i) {
    a[i] = *(const bf16x8*)&smem[0][0][(wm * 64 + i * 16 + l15) * 32 + sl];
    b[i] = *(const bf16x8*)&smem[0][1][(wn * 128 + i * 16 + l15) * 32 + sl];
  }

#pragma unroll 2
  for (int t = 0; t < NT; ++t) {
    const int bsel = t & 3, nsel = (t + 1) & 3, ssel = (t + 3) & 3;
    const bool do_stage = (t + 3) < NT;
    const bool have_next = (t + 1) < NT;
    const int knext = (t + 3) * 32;
    const u16* Asc = &smem[bsel][0][0];
    const u16* Bsc = &smem[bsel][1][0];
    const u16* Asn = &smem[nsel][0][0];
    const u16* Bsn = &smem[nsel][1][0];

    // ---- G1: read bh (B cols 64-127, this tile); MFMA acc[0..1][0..3] ----
    bf16x8 bh[4];
#pragma unroll
    for (int i = 0; i < 4; ++i)
      bh[i] = *(const bf16x8*)&Bsc[(wn * 128 + (4 + i) * 16 + l15) * 32 + sl];
    __builtin_amdgcn_sched_barrier(0);
    __builtin_amdgcn_s_setprio(1);
#pragma unroll
    for (int mi = 0; mi < 2; ++mi)
#pragma unroll
      for (int ni = 0; ni < 4; ++ni)
        acc[mi][ni] = __builtin_amdgcn_mfma_f32_16x16x32_bf16(a[mi], b[ni], acc[mi][ni], 0, 0, 0);
    __builtin_amdgcn_s_setprio(0);

    // ---- G2: read a2 (next tile, all A); MFMA acc[2..3][0..3] ----
    bf16x8 a2[4], b2[4];
    if (have_next) {
#pragma unroll
      for (int i = 0; i < 4; ++i)
        a2[i] = *(const bf16x8*)&Asn[(wm * 64 + i * 16 + l15) * 32 + sl];
    }
    __builtin_amdgcn_sched_barrier(0);
    __builtin_amdgcn_s_setprio(1);
#pragma unroll
    for (int mi = 2; mi < 4; ++mi)
#pragma unroll
      for (int ni = 0; ni < 4; ++ni)
        acc[mi][ni] = __builtin_amdgcn_mfma_f32_16x16x32_bf16(a[mi], b[ni], acc[mi][ni], 0, 0, 0);
    __builtin_amdgcn_s_setprio(0);

    // ---- G3: read b2 (next tile, B cols 0-63); DMA A(t+3); acc[0..1][4..7] --
    if (have_next) {
#pragma unroll
      for (int i = 0; i < 4; ++i)
        b2[i] = *(const bf16x8*)&Bsn[(wn * 128 + i * 16 + l15) * 32 + sl];
    }
    if (do_stage) {
#pragma unroll
      for (int call = 0; call < 2; ++call)
        async_copy16(&Ab[knext + soff[call]], &smem[ssel][0][cb[call]]);
    }
    __builtin_amdgcn_sched_barrier(0);
    __builtin_amdgcn_s_setprio(1);
#pragma unroll
    for (int mi = 0; mi < 2; ++mi)
#pragma unroll
      for (int ni = 0; ni < 4; ++ni)
        acc[mi][4 + ni] = __builtin_amdgcn_mfma_f32_16x16x32_bf16(a[mi], bh[ni], acc[mi][4 + ni], 0, 0, 0);
    __builtin_amdgcn_s_setprio(0);

    // ---- G4: DMA B(t+3); MFMA acc[2..3][4..7] ----
    if (do_stage) {
#pragma unroll
      for (int call = 0; call < 2; ++call)
        async_copy16(&Bb[knext + soff[call]], &smem[ssel][1][cb[call]]);
    }
    __builtin_amdgcn_sched_barrier(0);
    __builtin_amdgcn_s_setprio(1);
#pragma unroll
    for (int mi = 2; mi < 4; ++mi)
#pragma unroll
      for (int ni = 0; ni < 4; ++ni)
        acc[mi][4 + ni] = __builtin_amdgcn_mfma_f32_16x16x32_bf16(a[mi], bh[ni], acc[mi][4 + ni], 0, 0, 0);
    __builtin_amdgcn_s_setprio(0);

    // ---- tile boundary: publish t+2, seal reads (identical to round 6) ----
    if (t < NT - 2) {
      if (t < NT - 3) asm volatile("s_waitcnt vmcnt(4)" ::: "memory");
      else            asm volatile("s_waitcnt vmcnt(0)" ::: "memory");
      __builtin_amdgcn_s_barrier();
      asm volatile("" ::: "memory");
    }
    if (have_next) {
#pragma unroll
      for (int i = 0; i < 4; ++i) { a[i] = a2[i]; b[i] = b2[i]; }
    }
  }

  // epilogue: C/D layout col=lane&15, row=(lane>>4)*4+reg
  if (MODE == 0 && col0 >= 5120) {               // V section -> Vt directly
#pragma unroll
    for (int mi = 0; mi < 4; ++mi)
#pragma unroll
      for (int ni = 0; ni < 8; ++ni) {
        const int col = col0 + wn * 128 + ni * 16 + l15;
        const int dcol = col - 5120, kvh = dcol >> 7, d = dcol & 127;
        const int row = row0 + wm * 64 + mi * 16 + qd * 4;  // token, r=0
        const int bb = row >> 10, p = row & 1023;
        ushort4 pk;
        pk.x = f2bf(acc[mi][ni][0]); pk.y = f2bf(acc[mi][ni][1]);
        pk.z = f2bf(acc[mi][ni][2]); pk.w = f2bf(acc[mi][ni][3]);
        *(ushort4*)&Vt[(((size_t)(bb * 8 + kvh) * 128) + d) * 1024 + p] = pk;
      }
    return;
  }
  if (MODE == 0) {
    // Q/K tile: fused RoPE. Wave owns one full head (128 cols); pair (d,d+64)
    // is (ni, ni+4); freq index i = ni*16 + l15 (0..63).
    const int c0w = col0 + wn * 128;
    float fi[4];
#pragma unroll
    for (int ni = 0; ni < 4; ++ni) fi[ni] = invf[ni * 16 + l15];
    u16* C16 = (u16*)Cv;
#pragma unroll
    for (int mi = 0; mi < 4; ++mi) {
      const int rbase = row0 + wm * 64 + mi * 16 + qd * 4;
#pragma unroll
      for (int r = 0; r < 4; ++r) {
        const float pv = (float)pos[rbase + r];
        const size_t rowoff = (size_t)(rbase + r) * ldc + c0w;
#pragma unroll
        for (int ni = 0; ni < 4; ++ni) {
          const float x1 = acc[mi][ni][r], x2 = acc[mi][ni + 4][r];
          float s, c;
          __sincosf(pv * fi[ni], &s, &c);
          C16[rowoff + ni * 16 + l15]      = f2bf(x1 * c - x2 * s);
          C16[rowoff + 64 + ni * 16 + l15] = f2bf(x2 * c + x1 * s);
        }
      }
    }
    return;
  }
  // MODE 1: plain f32 C
#pragma unroll
  for (int mi = 0; mi < 4; ++mi)
#pragma unroll
    for (int ni = 0; ni < 8; ++ni)
#pragma unroll
      for (int r = 0; r < 4; ++r) {
        int row = row0 + wm * 64 + mi * 16 + qd * 4 + r;
        int col = col0 + wn * 128 + ni * 16 + l15;
        ((float*)Cv)[(size_t)row * ldc + col] = acc[mi][ni][r];
      }
}

// ---------------- flash attention ----------------
// block = (q-tile 128, head, batch); 8 waves x 16 q-rows; kv-tile 64.
// QK^T: A=Q frags (regs), B=K (LDS [kv][d] stride 136; 2-way banks = free).
// softmax: C-layout rows, quad-shuffle reductions; P -> per-wave LDS
// [q][kv] stride 68 (C->A layout round trip). PV: O^T acc, A=Vt (LDS [d][kv]
// stride 68). LDS total 52224 B.
__global__ __launch_bounds__(512, 4) void attn_kernel(const u16* __restrict__ qkv,
                                                      const u16* __restrict__ vt,
                                                      u16* __restrict__ ao) {
  __shared__ __align__(16) u16 Ks[64 * 136];
  __shared__ __align__(16) u16 Vts[128 * 68];
  __shared__ __align__(16) u16 Ps[8][16 * 68];

  const int tid = threadIdx.x;
  const int lane = tid & 63, wave = tid >> 6;
  const int l15 = lane & 15, qd = lane >> 4;
  const int qt = blockIdx.x, h = blockIdx.y, b = blockIdx.z;
  const int q0 = qt * 128;
  const int kvh = h >> 2;                      // GQA groups=4
  const float scale = 0.08838834764831845f;    // 1/sqrt(128)

  bf16x8 qf[4];
  {
    const size_t qrow = (size_t)(b * SEQ + q0 + wave * 16 + l15) * QKV_COLS + h * HDIM;
#pragma unroll
    for (int s = 0; s < 4; ++s) qf[s] = *(const bf16x8*)&qkv[qrow + s * 32 + qd * 8];
  }

  f32x4 o[8] = {};
  float mrow[4] = {-__builtin_inff(), -__builtin_inff(), -__builtin_inff(), -__builtin_inff()};
  float lrow[4] = {0.f, 0.f, 0.f, 0.f};

  const int nkt = qt * 2 + 2;                  // causal: kv tiles 0..(q0+128)/64
  const size_t vbase0 = ((size_t)(b * NKVH + kvh) * HDIM) * SEQ;
  for (int kt = 0; kt < nkt; ++kt) {
    const int kv0 = kt * 64;
#pragma unroll
    for (int rnd = 0; rnd < 2; ++rnd) {        // K tile [64][128], stride 136
      int c = tid + rnd * 512;
      int kv = c >> 4, dc = (c & 15) * 8;
      *(uint4*)&Ks[kv * 136 + dc] =
          *(const uint4*)&qkv[(size_t)(b * SEQ + kv0 + kv) * QKV_COLS + 4096 + kvh * HDIM + dc];
    }
#pragma unroll
    for (int rnd = 0; rnd < 2; ++rnd) {        // Vt tile [128][64], stride 68
      int c = tid + rnd * 512;
      int d = c >> 3, kc = (c & 7) * 8;
      *(uint4*)&Vts[d * 68 + kc] = *(const uint4*)&vt[vbase0 + (size_t)d * SEQ + kv0 + kc];
    }
    __syncthreads();

    f32x4 st[4] = {};
#pragma unroll
    for (int t = 0; t < 4; ++t)
#pragma unroll
      for (int s = 0; s < 4; ++s) {
        bf16x8 kf = *(const bf16x8*)&Ks[(t * 16 + l15) * 136 + s * 32 + qd * 8];
        st[t] = __builtin_amdgcn_mfma_f32_16x16x32_bf16(qf[s], kf, st[t], 0, 0, 0);
      }

    float al[4];
#pragma unroll
    for (int r = 0; r < 4; ++r) {
      const int qpos = q0 + wave * 16 + qd * 4 + r;
      float sc[4];
#pragma unroll
      for (int t = 0; t < 4; ++t) {
        sc[t] = st[t][r] * scale;
        if (kv0 + t * 16 + l15 > qpos) sc[t] = -1e30f;
      }
      float mt = fmaxf(fmaxf(sc[0], sc[1]), fmaxf(sc[2], sc[3]));
      mt = fmaxf(mt, __shfl_xor(mt, 8));
      mt = fmaxf(mt, __shfl_xor(mt, 4));
      mt = fmaxf(mt, __shfl_xor(mt, 2));
      mt = fmaxf(mt, __shfl_xor(mt, 1));
      const float mn = fmaxf(mrow[r], mt);
      al[r] = __expf(mrow[r] - mn);
      float p[4], rs = 0.f;
#pragma unroll
      for (int t = 0; t < 4; ++t) { p[t] = __expf(sc[t] - mn); rs += p[t]; }
      rs += __shfl_xor(rs, 8);
      rs += __shfl_xor(rs, 4);
      rs += __shfl_xor(rs, 2);
      rs += __shfl_xor(rs, 1);
      lrow[r] = lrow[r] * al[r] + rs;
      mrow[r] = mn;
#pragma unroll
      for (int t = 0; t < 4; ++t)
        Ps[wave][(qd * 4 + r) * 68 + t * 16 + l15] = f2bf(p[t]);
    }
    asm volatile("s_waitcnt lgkmcnt(0)" ::: "memory");  // P visible wave-wide

    {  // broadcast alpha (row-indexed) to q=l15 lanes, rescale O^T
      const int srcl = (l15 >> 2) * 16;
      float a0 = __shfl(al[0], srcl), a1 = __shfl(al[1], srcl);
      float a2 = __shfl(al[2], srcl), a3 = __shfl(al[3], srcl);
      const int rr = l15 & 3;
      float aq = (rr & 2) ? ((rr & 1) ? a3 : a2) : ((rr & 1) ? a1 : a0);
#pragma unroll
      for (int dt = 0; dt < 8; ++dt) o[dt] *= aq;
    }
    {  // PV: O^T[d][q] += Vt[d][kv] * P^T[kv][q], kv split in 2 k-tiles of 32
      const bf16x8 pf0 = *(const bf16x8*)&Ps[wave][l15 * 68 + qd * 8];
      const bf16x8 pf1 = *(const bf16x8*)&Ps[wave][l15 * 68 + 32 + qd * 8];
#pragma unroll
      for (int dt = 0; dt < 8; ++dt) {
        const bf16x8 vf0 = *(const bf16x8*)&Vts[(dt * 16 + l15) * 68 + qd * 8];
        const bf16x8 vf1 = *(const bf16x8*)&Vts[(dt * 16 + l15) * 68 + 32 + qd * 8];
        o[dt] = __builtin_amdgcn_mfma_f32_16x16x32_bf16(vf0, pf0, o[dt], 0, 0, 0);
        o[dt] = __builtin_amdgcn_mfma_f32_16x16x32_bf16(vf1, pf1, o[dt], 0, 0, 0);
      }
    }
    __syncthreads();
  }

  {  // normalize by l (q-indexed), packed ushort4 stores of O^T
    const int srcl = (l15 >> 2) * 16;
    float l0 = __shfl(lrow[0], srcl), l1 = __shfl(lrow[1], srcl);
    float l2 = __shfl(lrow[2], srcl), l3 = __shfl(lrow[3], srcl);
    const int rr = l15 & 3;
    float lq = (rr & 2) ? ((rr & 1) ? l3 : l2) : ((rr & 1) ? l1 : l0);
    const float inv = 1.0f / lq;
    const size_t obase = (size_t)(b * SEQ + q0 + wave * 16 + l15) * (NHEAD * HDIM) + h * HDIM;
#pragma unroll
    for (int dt = 0; dt < 8; ++dt) {
      ushort4 pk;
      pk.x = f2bf(o[dt][0] * inv); pk.y = f2bf(o[dt][1] * inv);
      pk.z = f2bf(o[dt][2] * inv); pk.w = f2bf(o[dt][3] * inv);
      *(ushort4*)&ao[obase + dt * 16 + qd * 4] = pk;
    }
  }
}

// ---------------------------------------------------------------------------
extern "C" void kernel_launch(void* const* d_in, const int* in_sizes, int n_in,
                              void* d_out, int out_size, void* d_ws, size_t ws_size,
                              hipStream_t stream) {
  const float* X    = (const float*)d_in[0];
  const float* Wq   = (const float*)d_in[1];
  const float* Wk   = (const float*)d_in[2];
  const float* Wv   = (const float*)d_in[3];
  const float* Wo   = (const float*)d_in[4];
  const float* invf = (const float*)d_in[5];
  const int*   pos  = (const int*)d_in[8];
  float* out = (float*)d_out;

  char* ws = (char*)d_ws;
  u16* Xbf   = (u16*)(ws + 0);
  u16* Wqkvt = (u16*)(ws + 33554432);
  u16* Wot   = (u16*)(ws + 83886080);
  u16* QKV   = (u16*)(ws + 117440512);
  u16* Vt    = (u16*)(ws + 167772160);
  u16* AO    = Xbf;  // reuse: Xbf dead after GEMM1

  dim3 tb32(32, 32);
  cast_f32_bf16<<<16384, 256, 0, stream>>>(X, Xbf, 16777216);
  transpose_f32_bf16<<<dim3(128, 128), tb32, 0, stream>>>(Wq, Wqkvt, 4096, 4096);
  transpose_f32_bf16<<<dim3(32, 128),  tb32, 0, stream>>>(Wk, Wqkvt + (size_t)4096 * 4096, 4096, 1024);
  transpose_f32_bf16<<<dim3(32, 128),  tb32, 0, stream>>>(Wv, Wqkvt + (size_t)5120 * 4096, 4096, 1024);
  transpose_f32_bf16<<<dim3(128, 128), tb32, 0, stream>>>(Wo, Wot, 4096, 4096);

  // grid = flattened (N/256)*(M/256); nbx passed for in-kernel decode
  gemm_bt<0><<<dim3(24 * 16), 512, 0, stream>>>(Xbf, Wqkvt, QKV, Vt, invf, pos,
                                                4096, 6144, 4096, 6144, 24);
  attn_kernel<<<dim3(8, 32, 4), 512, 0, stream>>>(QKV, Vt, AO);
  gemm_bt<1><<<dim3(16 * 16), 512, 0, stream>>>(AO, Wot, out, Vt, nullptr, nullptr,
                                                4096, 4096, 4096, 4096, 16);
}

// Round 5
// 805.758 us; speedup vs baseline: 1.0147x; 1.0147x over previous
//
#include <hip/hip_runtime.h>
#include <cstdint>
#include <cstddef>

// ---------------------------------------------------------------------------
// LlamaAttention prefill, MI355X/gfx950.
// Round 8: R6 loop grouping + R7 wave shape/fused RoPE.
//  R7 post-mortem: 4 granules/tile regressed gemm 234->270 (MfmaUtil 38->33.6)
//  -- 4x sched_barrier+setprio per tile fence every 8-MFMA burst from its
//  neighbor's ds_reads (over-pinning, m141-class). R6's 2-phase slip grouping
//  (16-MFMA bursts, reads issued a full phase ahead) measured best (234).
//  This round: 2-phase slip loop, mapped onto the 4Mx2N wave shape so the
//  fused-RoPE epilogue (validated in R7, deletes rope_kernel) is kept:
//   phase A {read bh (B cols 64-127, buf t); DMA A(t+3); 16 MFMA acc[*][0..3]}
//   phase B {read a2,b2 (buf t+1);           DMA B(t+3); 16 MFMA acc[*][4..7]}
//   boundary {vmcnt(4) -> publish t+2, keep t+3 in flight; s_barrier}.
//  Sync structure (ring-4 buffers, 3-ahead staging, one vmcnt+barrier per
//  tile) identical to R6/R7.
// Workspace layout (bytes): total 176,160,768 (168 MiB)
//   [0,32M)      Xbf  (4096x4096 bf16)  -- reused as AO after GEMM1
//   [32M,80M)    Wqkvt (6144x4096 bf16, B^T)
//   [80M,112M)   Wot   (4096x4096 bf16, B^T)
//   [112M,160M)  QKV   (4096x6144 bf16, Q/K pre-roped; V section poisoned)
//   [160M,168M)  Vt    (32 bh x 128 d x 1024 p bf16)
// ---------------------------------------------------------------------------

typedef unsigned short u16;
typedef __bf16 bf16x8 __attribute__((ext_vector_type(8)));
typedef float  f32x4  __attribute__((ext_vector_type(4)));

#define SEQ 1024
#define QKV_COLS 6144
#define NHEAD 32
#define NKVH 8
#define HDIM 128

__device__ __forceinline__ u16 f2bf(float f) {
  union { float f; uint32_t u; } v; v.f = f;
  return (u16)((v.u + 0x7fffu + ((v.u >> 16) & 1u)) >> 16);  // RNE
}
__device__ __forceinline__ float bf2f(u16 x) {
  union { uint32_t u; float f; } v; v.u = ((uint32_t)x) << 16;
  return v.f;
}

// async global->LDS DMA, 16B per lane. LDS dest: wave-uniform base + lane*16.
typedef __attribute__((address_space(1))) const uint32_t g_u32;
typedef __attribute__((address_space(3))) uint32_t l_u32;
__device__ __forceinline__ void async_copy16(const u16* g, u16* lds_base) {
  __builtin_amdgcn_global_load_lds((g_u32*)g, (l_u32*)lds_base, 16, 0, 0);
}

// ---------------- fp32 -> bf16 flat cast (X) ----------------
__global__ void cast_f32_bf16(const float* __restrict__ in, u16* __restrict__ out, int n) {
  int i = (blockIdx.x * 256 + threadIdx.x) * 4;
  if (i >= n) return;
  float4 v = *(const float4*)&in[i];
  uint2 pk;
  pk.x = (uint32_t)f2bf(v.x) | ((uint32_t)f2bf(v.y) << 16);
  pk.y = (uint32_t)f2bf(v.z) | ((uint32_t)f2bf(v.w) << 16);
  *(uint2*)&out[i] = pk;
}

// ---------------- transpose fp32 [R][C] -> bf16 [C][R] ----------------
__global__ void transpose_f32_bf16(const float* __restrict__ in, u16* __restrict__ out,
                                   int R, int C) {
  __shared__ float tile[32][33];
  int c0 = blockIdx.x * 32, r0 = blockIdx.y * 32;
  int tx = threadIdx.x, ty = threadIdx.y;
  tile[ty][tx] = in[(size_t)(r0 + ty) * C + c0 + tx];
  __syncthreads();
  out[(size_t)(c0 + ty) * R + r0 + tx] = f2bf(tile[tx][ty]);
}

// ---------------- bf16 GEMM: C[M][N] = A[M][K] * Bt[N][K]^T ----------------
// 256x256 tile, 8 waves (4Mx2N), wave tile 64x128 (4x8 frags of 16x16x32).
// BK=32. 4 LDS buffers; staging 3 tiles ahead; boundary = vmcnt(4)+s_barrier
// (publishes tile t+2; t+1 was published at the previous boundary, so
// next-tile register prefetch during tile t is legal; t+3 stays in flight).
// Per tile, 2 phases of 16 MFMA with reads issued a full phase ahead:
//  A: read bh[0..3] (B cols 64-127, buf t); DMA A(t+3); MFMA acc[0..3][0..3]
//  B: read a2,b2    (buf t+1);              DMA B(t+3); MFMA acc[0..3][4..7]
// Frag-read swizzle: LDS chunk slot j of row r holds global chunk
// j ^ (r&3) ^ ((r>>2)&3); row bases are multiples of 16 so the read offset
// depends only on the lane: sl = (qd ^ (l15&3) ^ (l15>>2))*8.
// MODE 0: V col-tiles (>=5120) -> Vt[bh][d][p]; Q/K tiles get RoPE applied
//         in-register (pairs (ni,ni+4) = cols d,d+64 of the wave's head).
// MODE 1: f32 C.
template <int MODE>
__global__ __launch_bounds__(512, 2) void gemm_bt(const u16* __restrict__ A,
                                                  const u16* __restrict__ Bt,
                                                  void* __restrict__ Cv,
                                                  u16* __restrict__ Vt,
                                                  const float* __restrict__ invf,
                                                  const int* __restrict__ pos,
                                                  int M, int N, int K, int ldc,
                                                  int nbx) {
  __shared__ __align__(16) u16 smem[4][2][256 * 32];   // [buf][A|B], 128 KiB

  const int tid = threadIdx.x;
  const int lane = tid & 63, wave = tid >> 6;
  const int l15 = lane & 15, qd = lane >> 4;
  const int wm = wave & 3, wn = wave >> 2;             // 4M x 2N

  // XCD-aware bijective block swizzle (nwg % 8 == 0 for our shapes)
  const int nwg = gridDim.x;
  const int bid = (int)blockIdx.x;
  const int swz = (bid & 7) * (nwg >> 3) + (bid >> 3);
  const int bx = swz % nbx, by = swz / nbx;
  const int row0 = by * 256, col0 = bx * 256;

  const int sl = (qd ^ (l15 & 3) ^ (l15 >> 2)) * 8;   // swizzled frag chunk

  // staging: per-thread pre-swizzled global source offset + wave LDS base
  int soff[2], cb[2];
#pragma unroll
  for (int call = 0; call < 2; ++call) {
    const int c = call * 512 + tid;              // linear LDS 16B-chunk index
    const int r = c >> 2, j = c & 3;             // row, chunk slot
    const int src = j ^ (r & 3) ^ ((r >> 2) & 3);
    soff[call] = r * K + src * 8;
    cb[call] = (call * 512 + wave * 64) * 8;     // wave-uniform dest (u16 idx)
  }

  const u16* Ab = A + (size_t)row0 * K;
  const u16* Bb = Bt + (size_t)col0 * K;
  const int NT = K >> 5;                         // K-tiles (K=4096 -> 128)

  f32x4 acc[4][8] = {};

  // -------- prologue: stage tiles 0..2 (12 loads), publish 0 and 1 --------
#pragma unroll
  for (int tt = 0; tt < 3; ++tt) {
#pragma unroll
    for (int call = 0; call < 2; ++call)
      async_copy16(&Ab[tt * 32 + soff[call]], &smem[tt][0][cb[call]]);
#pragma unroll
    for (int call = 0; call < 2; ++call)
      async_copy16(&Bb[tt * 32 + soff[call]], &smem[tt][1][cb[call]]);
  }
  asm volatile("s_waitcnt vmcnt(4)" ::: "memory");   // tiles 0,1 landed
  __builtin_amdgcn_s_barrier();
  asm volatile("" ::: "memory");

  // register prefetch: tile-0 A (all 4 frags) + B cols 0-63
  bf16x8 a[4], b[4];
#pragma unroll
  for (int i = 0; i < 4; ++i) {
    a[i] = *(const bf16x8*)&smem[0][0][(wm * 64 + i * 16 + l15) * 32 + sl];
    b[i] = *(const bf16x8*)&smem[0][1][(wn * 128 + i * 16 + l15) * 32 + sl];
  }

#pragma unroll 2
  for (int t = 0; t < NT; ++t) {
    const int bsel = t & 3, nsel = (t + 1) & 3, ssel = (t + 3) & 3;
    const bool do_stage = (t + 3) < NT;
    const bool have_next = (t + 1) < NT;
    const int knext = (t + 3) * 32;
    const u16* Bsc = &smem[bsel][1][0];
    const u16* Asn = &smem[nsel][0][0];
    const u16* Bsn = &smem[nsel][1][0];

    // ---- phase A: read bh (this tile); DMA A(t+3); MFMA acc[*][0..3] ----
    bf16x8 bh[4];
#pragma unroll
    for (int i = 0; i < 4; ++i)
      bh[i] = *(const bf16x8*)&Bsc[(wn * 128 + (4 + i) * 16 + l15) * 32 + sl];
    if (do_stage) {
#pragma unroll
      for (int call = 0; call < 2; ++call)
        async_copy16(&Ab[knext + soff[call]], &smem[ssel][0][cb[call]]);
    }
    __builtin_amdgcn_sched_barrier(0);
    __builtin_amdgcn_s_setprio(1);
#pragma unroll
    for (int mi = 0; mi < 4; ++mi)
#pragma unroll
      for (int ni = 0; ni < 4; ++ni)
        acc[mi][ni] = __builtin_amdgcn_mfma_f32_16x16x32_bf16(a[mi], b[ni], acc[mi][ni], 0, 0, 0);
    __builtin_amdgcn_s_setprio(0);

    // ---- phase B: read next tile a2/b2; DMA B(t+3); MFMA acc[*][4..7] ----
    bf16x8 a2[4], b2[4];
    if (have_next) {
#pragma unroll
      for (int i = 0; i < 4; ++i) {
        a2[i] = *(const bf16x8*)&Asn[(wm * 64 + i * 16 + l15) * 32 + sl];
        b2[i] = *(const bf16x8*)&Bsn[(wn * 128 + i * 16 + l15) * 32 + sl];
      }
    }
    if (do_stage) {
#pragma unroll
      for (int call = 0; call < 2; ++call)
        async_copy16(&Bb[knext + soff[call]], &smem[ssel][1][cb[call]]);
    }
    __builtin_amdgcn_sched_barrier(0);
    __builtin_amdgcn_s_setprio(1);
#pragma unroll
    for (int mi = 0; mi < 4; ++mi)
#pragma unroll
      for (int ni = 0; ni < 4; ++ni)
        acc[mi][4 + ni] = __builtin_amdgcn_mfma_f32_16x16x32_bf16(a[mi], bh[ni], acc[mi][4 + ni], 0, 0, 0);
    __builtin_amdgcn_s_setprio(0);

    // ---- tile boundary: publish t+2, keep t+3 in flight ----
    if (t < NT - 2) {
      if (t < NT - 3) asm volatile("s_waitcnt vmcnt(4)" ::: "memory");
      else            asm volatile("s_waitcnt vmcnt(0)" ::: "memory");
      __builtin_amdgcn_s_barrier();
      asm volatile("" ::: "memory");
    }
    if (have_next) {
#pragma unroll
      for (int i = 0; i < 4; ++i) { a[i] = a2[i]; b[i] = b2[i]; }
    }
  }

  // epilogue: C/D layout col=lane&15, row=(lane>>4)*4+reg
  if (MODE == 0 && col0 >= 5120) {               // V section -> Vt directly
#pragma unroll
    for (int mi = 0; mi < 4; ++mi)
#pragma unroll
      for (int ni = 0; ni < 8; ++ni) {
        const int col = col0 + wn * 128 + ni * 16 + l15;
        const int dcol = col - 5120, kvh = dcol >> 7, d = dcol & 127;
        const int row = row0 + wm * 64 + mi * 16 + qd * 4;  // token, r=0
        const int bb = row >> 10, p = row & 1023;
        ushort4 pk;
        pk.x = f2bf(acc[mi][ni][0]); pk.y = f2bf(acc[mi][ni][1]);
        pk.z = f2bf(acc[mi][ni][2]); pk.w = f2bf(acc[mi][ni][3]);
        *(ushort4*)&Vt[(((size_t)(bb * 8 + kvh) * 128) + d) * 1024 + p] = pk;
      }
    return;
  }
  if (MODE == 0) {
    // Q/K tile: fused RoPE. Wave owns one full head (128 cols); pair (d,d+64)
    // is (ni, ni+4); freq index i = ni*16 + l15 (0..63).
    const int c0w = col0 + wn * 128;
    float fi[4];
#pragma unroll
    for (int ni = 0; ni < 4; ++ni) fi[ni] = invf[ni * 16 + l15];
    u16* C16 = (u16*)Cv;
#pragma unroll
    for (int mi = 0; mi < 4; ++mi) {
      const int rbase = row0 + wm * 64 + mi * 16 + qd * 4;
#pragma unroll
      for (int r = 0; r < 4; ++r) {
        const float pv = (float)pos[rbase + r];
        const size_t rowoff = (size_t)(rbase + r) * ldc + c0w;
#pragma unroll
        for (int ni = 0; ni < 4; ++ni) {
          const float x1 = acc[mi][ni][r], x2 = acc[mi][ni + 4][r];
          float s, c;
          __sincosf(pv * fi[ni], &s, &c);
          C16[rowoff + ni * 16 + l15]      = f2bf(x1 * c - x2 * s);
          C16[rowoff + 64 + ni * 16 + l15] = f2bf(x2 * c + x1 * s);
        }
      }
    }
    return;
  }
  // MODE 1: plain f32 C
#pragma unroll
  for (int mi = 0; mi < 4; ++mi)
#pragma unroll
    for (int ni = 0; ni < 8; ++ni)
#pragma unroll
      for (int r = 0; r < 4; ++r) {
        int row = row0 + wm * 64 + mi * 16 + qd * 4 + r;
        int col = col0 + wn * 128 + ni * 16 + l15;
        ((float*)Cv)[(size_t)row * ldc + col] = acc[mi][ni][r];
      }
}

// ---------------- flash attention ----------------
// block = (q-tile 128, head, batch); 8 waves x 16 q-rows; kv-tile 64.
// QK^T: A=Q frags (regs), B=K (LDS [kv][d] stride 136; 2-way banks = free).
// softmax: C-layout rows, quad-shuffle reductions; P -> per-wave LDS
// [q][kv] stride 68 (C->A layout round trip). PV: O^T acc, A=Vt (LDS [d][kv]
// stride 68). LDS total 52224 B.
__global__ __launch_bounds__(512, 4) void attn_kernel(const u16* __restrict__ qkv,
                                                      const u16* __restrict__ vt,
                                                      u16* __restrict__ ao) {
  __shared__ __align__(16) u16 Ks[64 * 136];
  __shared__ __align__(16) u16 Vts[128 * 68];
  __shared__ __align__(16) u16 Ps[8][16 * 68];

  const int tid = threadIdx.x;
  const int lane = tid & 63, wave = tid >> 6;
  const int l15 = lane & 15, qd = lane >> 4;
  const int qt = blockIdx.x, h = blockIdx.y, b = blockIdx.z;
  const int q0 = qt * 128;
  const int kvh = h >> 2;                      // GQA groups=4
  const float scale = 0.08838834764831845f;    // 1/sqrt(128)

  bf16x8 qf[4];
  {
    const size_t qrow = (size_t)(b * SEQ + q0 + wave * 16 + l15) * QKV_COLS + h * HDIM;
#pragma unroll
    for (int s = 0; s < 4; ++s) qf[s] = *(const bf16x8*)&qkv[qrow + s * 32 + qd * 8];
  }

  f32x4 o[8] = {};
  float mrow[4] = {-__builtin_inff(), -__builtin_inff(), -__builtin_inff(), -__builtin_inff()};
  float lrow[4] = {0.f, 0.f, 0.f, 0.f};

  const int nkt = qt * 2 + 2;                  // causal: kv tiles 0..(q0+128)/64
  const size_t vbase0 = ((size_t)(b * NKVH + kvh) * HDIM) * SEQ;
  for (int kt = 0; kt < nkt; ++kt) {
    const int kv0 = kt * 64;
#pragma unroll
    for (int rnd = 0; rnd < 2; ++rnd) {        // K tile [64][128], stride 136
      int c = tid + rnd * 512;
      int kv = c >> 4, dc = (c & 15) * 8;
      *(uint4*)&Ks[kv * 136 + dc] =
          *(const uint4*)&qkv[(size_t)(b * SEQ + kv0 + kv) * QKV_COLS + 4096 + kvh * HDIM + dc];
    }
#pragma unroll
    for (int rnd = 0; rnd < 2; ++rnd) {        // Vt tile [128][64], stride 68
      int c = tid + rnd * 512;
      int d = c >> 3, kc = (c & 7) * 8;
      *(uint4*)&Vts[d * 68 + kc] = *(const uint4*)&vt[vbase0 + (size_t)d * SEQ + kv0 + kc];
    }
    __syncthreads();

    f32x4 st[4] = {};
#pragma unroll
    for (int t = 0; t < 4; ++t)
#pragma unroll
      for (int s = 0; s < 4; ++s) {
        bf16x8 kf = *(const bf16x8*)&Ks[(t * 16 + l15) * 136 + s * 32 + qd * 8];
        st[t] = __builtin_amdgcn_mfma_f32_16x16x32_bf16(qf[s], kf, st[t], 0, 0, 0);
      }

    float al[4];
#pragma unroll
    for (int r = 0; r < 4; ++r) {
      const int qpos = q0 + wave * 16 + qd * 4 + r;
      float sc[4];
#pragma unroll
      for (int t = 0; t < 4; ++t) {
        sc[t] = st[t][r] * scale;
        if (kv0 + t * 16 + l15 > qpos) sc[t] = -1e30f;
      }
      float mt = fmaxf(fmaxf(sc[0], sc[1]), fmaxf(sc[2], sc[3]));
      mt = fmaxf(mt, __shfl_xor(mt, 8));
      mt = fmaxf(mt, __shfl_xor(mt, 4));
      mt = fmaxf(mt, __shfl_xor(mt, 2));
      mt = fmaxf(mt, __shfl_xor(mt, 1));
      const float mn = fmaxf(mrow[r], mt);
      al[r] = __expf(mrow[r] - mn);
      float p[4], rs = 0.f;
#pragma unroll
      for (int t = 0; t < 4; ++t) { p[t] = __expf(sc[t] - mn); rs += p[t]; }
      rs += __shfl_xor(rs, 8);
      rs += __shfl_xor(rs, 4);
      rs += __shfl_xor(rs, 2);
      rs += __shfl_xor(rs, 1);
      lrow[r] = lrow[r] * al[r] + rs;
      mrow[r] = mn;
#pragma unroll
      for (int t = 0; t < 4; ++t)
        Ps[wave][(qd * 4 + r) * 68 + t * 16 + l15] = f2bf(p[t]);
    }
    asm volatile("s_waitcnt lgkmcnt(0)" ::: "memory");  // P visible wave-wide

    {  // broadcast alpha (row-indexed) to q=l15 lanes, rescale O^T
      const int srcl = (l15 >> 2) * 16;
      float a0 = __shfl(al[0], srcl), a1 = __shfl(al[1], srcl);
      float a2 = __shfl(al[2], srcl), a3 = __shfl(al[3], srcl);
      const int rr = l15 & 3;
      float aq = (rr & 2) ? ((rr & 1) ? a3 : a2) : ((rr & 1) ? a1 : a0);
#pragma unroll
      for (int dt = 0; dt < 8; ++dt) o[dt] *= aq;
    }
    {  // PV: O^T[d][q] += Vt[d][kv] * P^T[kv][q], kv split in 2 k-tiles of 32
      const bf16x8 pf0 = *(const bf16x8*)&Ps[wave][l15 * 68 + qd * 8];
      const bf16x8 pf1 = *(const bf16x8*)&Ps[wave][l15 * 68 + 32 + qd * 8];
#pragma unroll
      for (int dt = 0; dt < 8; ++dt) {
        const bf16x8 vf0 = *(const bf16x8*)&Vts[(dt * 16 + l15) * 68 + qd * 8];
        const bf16x8 vf1 = *(const bf16x8*)&Vts[(dt * 16 + l15) * 68 + 32 + qd * 8];
        o[dt] = __builtin_amdgcn_mfma_f32_16x16x32_bf16(vf0, pf0, o[dt], 0, 0, 0);
        o[dt] = __builtin_amdgcn_mfma_f32_16x16x32_bf16(vf1, pf1, o[dt], 0, 0, 0);
      }
    }
    __syncthreads();
  }

  {  // normalize by l (q-indexed), packed ushort4 stores of O^T
    const int srcl = (l15 >> 2) * 16;
    float l0 = __shfl(lrow[0], srcl), l1 = __shfl(lrow[1], srcl);
    float l2 = __shfl(lrow[2], srcl), l3 = __shfl(lrow[3], srcl);
    const int rr = l15 & 3;
    float lq = (rr & 2) ? ((rr & 1) ? l3 : l2) : ((rr & 1) ? l1 : l0);
    const float inv = 1.0f / lq;
    const size_t obase = (size_t)(b * SEQ + q0 + wave * 16 + l15) * (NHEAD * HDIM) + h * HDIM;
#pragma unroll
    for (int dt = 0; dt < 8; ++dt) {
      ushort4 pk;
      pk.x = f2bf(o[dt][0] * inv); pk.y = f2bf(o[dt][1] * inv);
      pk.z = f2bf(o[dt][2] * inv); pk.w = f2bf(o[dt][3] * inv);
      *(ushort4*)&ao[obase + dt * 16 + qd * 4] = pk;
    }
  }
}

// ---------------------------------------------------------------------------
extern "C" void kernel_launch(void* const* d_in, const int* in_sizes, int n_in,
                              void* d_out, int out_size, void* d_ws, size_t ws_size,
                              hipStream_t stream) {
  const float* X    = (const float*)d_in[0];
  const float* Wq   = (const float*)d_in[1];
  const float* Wk   = (const float*)d_in[2];
  const float* Wv   = (const float*)d_in[3];
  const float* Wo   = (const float*)d_in[4];
  const float* invf = (const float*)d_in[5];
  const int*   pos  = (const int*)d_in[8];
  float* out = (float*)d_out;

  char* ws = (char*)d_ws;
  u16* Xbf   = (u16*)(ws + 0);
  u16* Wqkvt = (u16*)(ws + 33554432);
  u16* Wot   = (u16*)(ws + 83886080);
  u16* QKV   = (u16*)(ws + 117440512);
  u16* Vt    = (u16*)(ws + 167772160);
  u16* AO    = Xbf;  // reuse: Xbf dead after GEMM1

  dim3 tb32(32, 32);
  cast_f32_bf16<<<16384, 256, 0, stream>>>(X, Xbf, 16777216);
  transpose_f32_bf16<<<dim3(128, 128), tb32, 0, stream>>>(Wq, Wqkvt, 4096, 4096);
  transpose_f32_bf16<<<dim3(32, 128),  tb32, 0, stream>>>(Wk, Wqkvt + (size_t)4096 * 4096, 4096, 1024);
  transpose_f32_bf16<<<dim3(32, 128),  tb32, 0, stream>>>(Wv, Wqkvt + (size_t)5120 * 4096, 4096, 1024);
  transpose_f32_bf16<<<dim3(128, 128), tb32, 0, stream>>>(Wo, Wot, 4096, 4096);

  // grid = flattened (N/256)*(M/256); nbx passed for in-kernel decode
  gemm_bt<0><<<dim3(24 * 16), 512, 0, stream>>>(Xbf, Wqkvt, QKV, Vt, invf, pos,
                                                4096, 6144, 4096, 6144, 24);
  attn_kernel<<<dim3(8, 32, 4), 512, 0, stream>>>(QKV, Vt, AO);
  gemm_bt<1><<<dim3(16 * 16), 512, 0, stream>>>(AO, Wot, out, Vt, nullptr, nullptr,
                                                4096, 4096, 4096, 4096, 16);
}